// Round 19
// baseline (399.561 us; speedup 1.0000x reference)
//
#include <hip/hip_runtime.h>
#include <hip/hip_bf16.h>
#include <cstdint>
#include <cstddef>

// MoE expert FFN: h = gelu(x @ w1[e]^T + b1[e]); out = h @ w2[e]^T + b2[e]
// R19: R18 frozen + ONE change: cvt(w2) INTERLEAVED into GEMM1's K-loop
// (software-pipelined, T14) instead of dedicated-last piggy blocks.
//   Dedicated piggy costs ~16-20us in all three placements (last=tail,
//   first=slot-squatting, scattered=post-epilogue tail). Interleaved: first
//   1024 GEMM blocks convert one 2KB slice per K-iter — f32 loads issued with
//   the staging burst (full MFMA phase + vmcnt-drain barrier before use),
//   cvt'd store fired the NEXT iter. 1024 x 16 x 256 x 8 = 33.5M = |w2|.
//   Validity guard uniform per (block,t). No dedicated slots, no tail.
//   - GEMM1: BK=64 single-A + dbuf B (48KB -> 3/CU), LDS-transpose epilogue
//     (R18: write-amp 197->131MB, -29us).
//   - GEMM2: BK=64 plain dbuf, scalar f32 epilogue.
//   - cvt2_build: cvt(inp)+cvt(w1)+tile table (240MB at HBM roofline).

typedef __bf16 bf16x8 __attribute__((ext_vector_type(8)));
typedef float f32x4 __attribute__((ext_vector_type(4)));
typedef unsigned short u16x8 __attribute__((ext_vector_type(8)));

#define BM 128
#define BN 128

__device__ __forceinline__ unsigned short f2bf(float f) {
  unsigned u = __builtin_bit_cast(unsigned, f);
  u += 0x7FFFu + ((u >> 16) & 1u);   // RNE
  return (unsigned short)(u >> 16);
}

__device__ __forceinline__ float fast_gelu(float v) {
  const float u = 0.7978845608028654f * (v + 0.044715f * v * v * v);
  const float t = 1.0f - 2.0f / (__expf(2.0f * u) + 1.0f);   // tanh(u)
  return 0.5f * v * (1.0f + t);
}

__device__ __forceinline__ void gload16(const void* g, void* lds) {
  __builtin_amdgcn_global_load_lds(
      (const __attribute__((address_space(1))) void*)g,
      (__attribute__((address_space(3))) void*)lds, 16, 0, 0);
}

__device__ __forceinline__ void cvt8(const float* __restrict__ src,
                                     unsigned short* __restrict__ dst, long i) {
  float4 a = *reinterpret_cast<const float4*>(src + i);
  float4 b = *reinterpret_cast<const float4*>(src + i + 4);
  u16x8 o;
  o[0] = f2bf(a.x); o[1] = f2bf(a.y); o[2] = f2bf(a.z); o[3] = f2bf(a.w);
  o[4] = f2bf(b.x); o[5] = f2bf(b.y); o[6] = f2bf(b.z); o[7] = f2bf(b.w);
  *reinterpret_cast<u16x8*>(dst + i) = o;
}

// ------- cvt(inp)+cvt(w1) + tile-table build, one dispatch -------------------
__global__ void cvt2_build(const float* __restrict__ s0,
                           unsigned short* __restrict__ d0, long n0,
                           const float* __restrict__ s1,
                           unsigned short* __restrict__ d1, long n1,
                           const int* __restrict__ cnt, int E,
                           int4* __restrict__ tbl, int* __restrict__ ntp) {
  if (blockIdx.x == 0 && threadIdx.x == 0) {
    int nt = 0, start = 0;
    for (int e = 0; e < E; ++e) {
      int c = cnt[e];
      for (int t = 0; t < c; t += BM) {
        int4 v; v.x = e; v.y = start + t; v.z = (c - t < BM ? c - t : BM); v.w = 0;
        tbl[nt++] = v;
      }
      start += c;
    }
    *ntp = nt;
  }
  long i = ((long)blockIdx.x * blockDim.x + threadIdx.x) * 8;
  const long stride = (long)gridDim.x * blockDim.x * 8;
  const long ntot = n0 + n1;
  for (; i < ntot; i += stride) {
    if (i < n0) cvt8(s0, d0, i);
    else        cvt8(s1, d1, i - n0);
  }
}

// ---------------- grouped GEMM (BK=64; SINGLEA selects buffering) ------------
// C[t,n] = A[t,:] . W[e][n,:] (+bias, opt gelu). A:[T,K] bf16, W:[E,N,K] bf16.
// PIGGY==2: interleaved cvt(w2) in the K-loop (SINGLEA path only).
// SINGLEA && OUTBF: LDS-transpose epilogue (coalesced 16B bf16 stores).
template <int GELU, int OUTBF, int PIGGY, int SINGLEA, int WPE>
__global__ __launch_bounds__(256, WPE) void grouped_gemm(
    const unsigned short* __restrict__ A, const unsigned short* __restrict__ W,
    const float* __restrict__ bias, void* __restrict__ Cv,
    const int4* __restrict__ tbl, const int* __restrict__ ntp,
    const int N, const int K,
    const float* __restrict__ pg_src, unsigned short* __restrict__ pg_dst,
    const long pg_n) {
  constexpr int BKT = 64;
  const int mt = blockIdx.y;
  const int bx = blockIdx.x;
  if (mt >= *ntp) return;
  const int4 ti = tbl[mt];
  const int e = ti.x, row0 = ti.y, rows = ti.z;
  const int bcol = bx * BN;

  constexpr int SABUF = SINGLEA ? 1 : 2;
  __shared__ alignas(16) unsigned short raw[(SABUF + 2) * BM * BKT];
  auto sA = [&](int b) { return &raw[b * BM * BKT]; };
  auto sB = [&](int b) { return &raw[(SABUF + b) * BN * BKT]; };

  const int tid = threadIdx.x;
  const int lane = tid & 63;
  const int wave = tid >> 6;
  const int wr = wave >> 1;  // 0..1
  const int wc = wave & 1;   // 0..1
  const int lr = lane & 15;
  const int lhi = lane >> 4; // 0..3

  const unsigned short* __restrict__ Wexp = W + (size_t)e * N * K;

  // ---- staging geometry (dest linear: wave*1024 + lane*16 + i*4096) --------
  constexpr int CH  = BKT / 8;     // 8 chunks of 16B per row
  constexpr int LPM = BKT / 16;    // 4 gload16 per matrix per thread
  constexpr int RPL = 2048 / BKT;  // 32 rows per load-block
  const int srow = wave * 8 + (lane >> 3);
  const int chn = lane & (CH - 1);
  const int cg = chn ^ (srow & (CH - 1));   // inverse swizzle, thread-constant

  const unsigned short* gA[LPM];
  const unsigned short* gB[LPM];
#pragma unroll
  for (int i = 0; i < LPM; ++i) {
    const int rA = srow + i * RPL;
    const int rc = rA < rows ? rA : rows - 1;     // clamp inside segment
    gA[i] = A + (size_t)(row0 + rc) * K + cg * 8;
    gB[i] = Wexp + (size_t)(bcol + srow + i * RPL) * K + cg * 8;
  }

  auto stage = [&](int kt, int bA, int bB) {
    char* da = (char*)sA(bA) + wave * 1024;
    char* db = (char*)sB(bB) + wave * 1024;
#pragma unroll
    for (int i = 0; i < LPM; ++i) {
      gload16(gA[i] + kt * BKT, da + i * 4096);
      gload16(gB[i] + kt * BKT, db + i * 4096);
    }
  };

  // ---- LDS read addressing (swizzled; measured conflict-free at BK=64) -----
  constexpr int KH = BKT / 32;     // 2 k-steps of 32 per tile
  int swo[KH];
#pragma unroll
  for (int kh = 0; kh < KH; ++kh)
    swo[kh] = ((kh * 4 + lhi) ^ (lr & (CH - 1))) * 8;
  const int aRowB = wr * 64 + lr;
  const int bRowB = wc * 64 + lr;

  f32x4 acc[4][4] = {};
  const int nk = K / BKT;

  // ---- interleaved-piggy state (PIGGY==2) -----------------------------------
  // Blocks flat < PIGF each convert one 2KB slice per K-iter; load at t,
  // store at t+1 (HBM latency hides under MFMA + the closing vmcnt drain).
  const int flat = mt * gridDim.x + bx;
  const long pgUnits = pg_n >> 11;                 // 256 thr x 8 floats
  const int PIGF = (int)((pgUnits + nk - 1) / nk);
  const bool pig = (PIGGY == 2) && (flat < PIGF);
  float4 pa, pb;
  long pi = -1;
  auto pigStore = [&]() {
    if (pi >= 0) {
      u16x8 o;
      o[0] = f2bf(pa.x); o[1] = f2bf(pa.y); o[2] = f2bf(pa.z); o[3] = f2bf(pa.w);
      o[4] = f2bf(pb.x); o[5] = f2bf(pb.y); o[6] = f2bf(pb.z); o[7] = f2bf(pb.w);
      *reinterpret_cast<u16x8*>(pg_dst + pi) = o;
    }
  };
  auto pigLoad = [&](int t) {
    const long i = (((long)flat * nk + t) * 256 + tid) * 8;
    if (i < pg_n) {
      pa = *reinterpret_cast<const float4*>(pg_src + i);
      pb = *reinterpret_cast<const float4*>(pg_src + i + 4);
      pi = i;
    } else {
      pi = -1;
    }
  };

  stage(0, 0, 0);
  __syncthreads();

  int buf = 0;
  if constexpr (SINGLEA) {
    // A single-buffered (L2-hot), B double-buffered (cold stream).
    for (int t = 0; t < nk; ++t) {
      bf16x8 af[4][KH], bfr[4][KH];
#pragma unroll
      for (int m = 0; m < 4; ++m) {
        const unsigned short* rp = &sA(0)[(aRowB + m * 16) * BKT];
#pragma unroll
        for (int kh = 0; kh < KH; ++kh)
          af[m][kh] = *reinterpret_cast<const bf16x8*>(rp + swo[kh]);
      }
#pragma unroll
      for (int n = 0; n < 4; ++n) {
        const unsigned short* rp = &sB(buf)[(bRowB + n * 16) * BKT];
#pragma unroll
        for (int kh = 0; kh < KH; ++kh)
          bfr[n][kh] = *reinterpret_cast<const bf16x8*>(rp + swo[kh]);
      }
      __syncthreads();               // all waves' reads retired -> sA reusable
      if (t + 1 < nk) stage(t + 1, 0, buf ^ 1);
      if (pig) { pigStore(); pigLoad(t); }   // store prev slice, load next
#pragma unroll
      for (int kh = 0; kh < KH; ++kh)
#pragma unroll
        for (int m = 0; m < 4; ++m)
#pragma unroll
          for (int n = 0; n < 4; ++n)
            acc[m][n] = __builtin_amdgcn_mfma_f32_16x16x32_bf16(
                af[m][kh], bfr[n][kh], acc[m][n], 0, 0, 0);
      __syncthreads();               // vmcnt drain: staged tile + pig load done
      buf ^= 1;
    }
    if (pig) pigStore();             // flush the last loaded slice
  } else {
    // Plain double-buffer (R13-proven for GEMM2).
    for (int t = 0; t < nk; ++t) {
      if (t + 1 < nk) stage(t + 1, buf ^ 1, buf ^ 1);
#pragma unroll
      for (int kh = 0; kh < KH; ++kh) {
        bf16x8 af[4], bfr[4];
#pragma unroll
        for (int m = 0; m < 4; ++m)
          af[m] = *reinterpret_cast<const bf16x8*>(
              &sA(buf)[(aRowB + m * 16) * BKT + swo[kh]]);
#pragma unroll
        for (int n = 0; n < 4; ++n)
          bfr[n] = *reinterpret_cast<const bf16x8*>(
              &sB(buf)[(bRowB + n * 16) * BKT + swo[kh]]);
#pragma unroll
        for (int m = 0; m < 4; ++m)
#pragma unroll
          for (int n = 0; n < 4; ++n)
            acc[m][n] = __builtin_amdgcn_mfma_f32_16x16x32_bf16(
                af[m], bfr[n], acc[m][n], 0, 0, 0);
      }
      __syncthreads();
      buf ^= 1;
    }
  }

  // Epilogue. C/D layout (m89): col = lane&15, row = (lane>>4)*4 + reg.
  const float* __restrict__ be = bias + (size_t)e * N;
  if constexpr (SINGLEA && OUTBF) {
    // LDS-transpose epilogue (R18): gelu+pack to LDS, coalesced 16B stores.
    unsigned short* tb = raw;
#pragma unroll
    for (int n = 0; n < 4; ++n) {
      const int col = wc * 64 + n * 16 + lr;         // tile-local 0..127
      const float bv = be[bcol + col];
#pragma unroll
      for (int m = 0; m < 4; ++m) {
#pragma unroll
        for (int j = 0; j < 4; ++j) {
          const int row = wr * 64 + m * 16 + (lhi << 2) + j;
          float v = acc[m][n][j] + bv;
          if (GELU) v = fast_gelu(v);
          tb[row * BN + col] = f2bf(v);
        }
      }
    }
    __syncthreads();
    unsigned short* __restrict__ hout = (unsigned short*)Cv;
#pragma unroll
    for (int i = 0; i < 8; ++i) {
      const int fl = i * 256 + tid;
      const int row = fl >> 4;                       // 16 threads per 256B row
      const int ch = fl & 15;
      if (row < rows)
        *reinterpret_cast<u16x8*>(&hout[(size_t)(row0 + row) * N + bcol + ch * 8]) =
            *reinterpret_cast<const u16x8*>(&tb[row * BN + ch * 8]);
    }
  } else {
    const int colBase = bcol + wc * 64 + lr;
    const int rowBase = wr * 64 + (lhi << 2);
#pragma unroll
    for (int n = 0; n < 4; ++n) {
      const int col = colBase + n * 16;
      const float bv = be[col];
#pragma unroll
      for (int m = 0; m < 4; ++m) {
        const int r0 = rowBase + m * 16;
#pragma unroll
        for (int j = 0; j < 4; ++j) {
          const int rr = r0 + j;
          if (rr < rows) {
            float v = acc[m][n][j] + bv;
            if (GELU) v = fast_gelu(v);
            const size_t idx = (size_t)(row0 + rr) * N + col;
            if (OUTBF) ((unsigned short*)Cv)[idx] = f2bf(v);
            else       ((float*)Cv)[idx] = v;
          }
        }
      }
    }
  }
}

extern "C" void kernel_launch(void* const* d_in, const int* in_sizes, int n_in,
                              void* d_out, int out_size, void* d_ws, size_t ws_size,
                              hipStream_t stream) {
  const float* inp = (const float*)d_in[0];
  const float* w1  = (const float*)d_in[1];
  const float* b1  = (const float*)d_in[2];
  const float* w2  = (const float*)d_in[3];
  const float* b2  = (const float*)d_in[4];
  const int*   cnt = (const int*)d_in[5];

  const int E = in_sizes[5];
  const int H = in_sizes[2] / E;       // b1 is [E,H]
  const int D = in_sizes[4] / E;       // b2 is [E,D]
  const int T = in_sizes[0] / D;       // inp is [T,D]

  char* ws = (char*)d_ws;
  int4* tbl = (int4*)ws;               // <= 72 entries
  int* ntp = (int*)(ws + 2048);
  size_t off = 4096;
  unsigned short* inp_bf = (unsigned short*)(ws + off); off += (size_t)T * D * 2;
  unsigned short* w1_bf  = (unsigned short*)(ws + off); off += (size_t)E * H * D * 2;
  unsigned short* w2_bf  = (unsigned short*)(ws + off); off += (size_t)E * D * H * 2;
  unsigned short* h_bf   = (unsigned short*)(ws + off); off += (size_t)T * H * 2;
  (void)ws_size; (void)n_in; (void)out_size;

  // cvt(inp)+cvt(w1) + tile-table build, one dispatch (GEMM1 deps).
  cvt2_build<<<2048, 256, 0, stream>>>(inp, inp_bf, (long)T * D,
                                       w1, w1_bf, (long)E * H * D,
                                       cnt, E, tbl, ntp);

  const int maxTiles = T / BM + E;
  // GEMM1: BK=64 single-A (48KB -> 3/CU), interleaved cvt(w2), LDS epilogue.
  dim3 g1(H / BN, maxTiles);
  grouped_gemm<1, 1, 2, 1, 3><<<g1, 256, 0, stream>>>(
      inp_bf, w1_bf, b1, h_bf, tbl, ntp, H, D,
      w2, w2_bf, (long)E * D * H);
  // GEMM2: BK=64 plain dbuf (R13-proven ~100us).
  dim3 g2(D / BN, maxTiles);
  grouped_gemm<0, 0, 0, 0, 2><<<g2, 256, 0, stream>>>(
      h_bf, w2_bf, b2, d_out, tbl, ntp, D, H,
      nullptr, nullptr, 0);
}

// Round 20
// 267.039 us; speedup vs baseline: 1.4963x; 1.4963x over previous
//
#include <hip/hip_runtime.h>
#include <hip/hip_bf16.h>
#include <cstdint>
#include <cstddef>

// MoE expert FFN: h = gelu(x @ w1[e]^T + b1[e]); out = h @ w2[e]^T + b2[e]
// R20: REVERT to R18 exactly — best measured config (268.1us).
//   R19's interleaved cvt(w2) regressed (133->265us): the per-iter syncthreads
//   vmcnt(0) drain put the piggy's cold f32 HBM loads (~900cy) on the K-loop
//   critical path. Dedicated-last remains the best of 4 measured placements.
// Config (all components at measured optima):
//   - cvt2_build: cvt(inp)+cvt(w1)+tile table, ~35us (HBM roofline for 240MB).
//   - GEMM1: BK=64, single-buffered A (L2-hot) + dbuf B (48KB -> 3 blocks/CU),
//     LDS-transpose epilogue (write-amp 197->131MB, R18: -29us), fast-gelu,
//     piggyback cvt(w2) as 8 dedicated-last grid rows. ~133us.
//   - GEMM2: BK=64 plain dbuf (grid-capped 2 blocks/CU), f32 epilogue. ~100us.

typedef __bf16 bf16x8 __attribute__((ext_vector_type(8)));
typedef float f32x4 __attribute__((ext_vector_type(4)));
typedef unsigned short u16x8 __attribute__((ext_vector_type(8)));

#define BM 128
#define BN 128

__device__ __forceinline__ unsigned short f2bf(float f) {
  unsigned u = __builtin_bit_cast(unsigned, f);
  u += 0x7FFFu + ((u >> 16) & 1u);   // RNE
  return (unsigned short)(u >> 16);
}

__device__ __forceinline__ float fast_gelu(float v) {
  const float u = 0.7978845608028654f * (v + 0.044715f * v * v * v);
  const float t = 1.0f - 2.0f / (__expf(2.0f * u) + 1.0f);   // tanh(u)
  return 0.5f * v * (1.0f + t);
}

__device__ __forceinline__ void gload16(const void* g, void* lds) {
  __builtin_amdgcn_global_load_lds(
      (const __attribute__((address_space(1))) void*)g,
      (__attribute__((address_space(3))) void*)lds, 16, 0, 0);
}

__device__ __forceinline__ void cvt8(const float* __restrict__ src,
                                     unsigned short* __restrict__ dst, long i) {
  float4 a = *reinterpret_cast<const float4*>(src + i);
  float4 b = *reinterpret_cast<const float4*>(src + i + 4);
  u16x8 o;
  o[0] = f2bf(a.x); o[1] = f2bf(a.y); o[2] = f2bf(a.z); o[3] = f2bf(a.w);
  o[4] = f2bf(b.x); o[5] = f2bf(b.y); o[6] = f2bf(b.z); o[7] = f2bf(b.w);
  *reinterpret_cast<u16x8*>(dst + i) = o;
}

// ------- cvt(inp)+cvt(w1) + tile-table build, one dispatch -------------------
__global__ void cvt2_build(const float* __restrict__ s0,
                           unsigned short* __restrict__ d0, long n0,
                           const float* __restrict__ s1,
                           unsigned short* __restrict__ d1, long n1,
                           const int* __restrict__ cnt, int E,
                           int4* __restrict__ tbl, int* __restrict__ ntp) {
  if (blockIdx.x == 0 && threadIdx.x == 0) {
    int nt = 0, start = 0;
    for (int e = 0; e < E; ++e) {
      int c = cnt[e];
      for (int t = 0; t < c; t += BM) {
        int4 v; v.x = e; v.y = start + t; v.z = (c - t < BM ? c - t : BM); v.w = 0;
        tbl[nt++] = v;
      }
      start += c;
    }
    *ntp = nt;
  }
  long i = ((long)blockIdx.x * blockDim.x + threadIdx.x) * 8;
  const long stride = (long)gridDim.x * blockDim.x * 8;
  const long ntot = n0 + n1;
  for (; i < ntot; i += stride) {
    if (i < n0) cvt8(s0, d0, i);
    else        cvt8(s1, d1, i - n0);
  }
}

// ---------------- grouped GEMM (BK=64; SINGLEA selects buffering) ------------
// C[t,n] = A[t,:] . W[e][n,:] (+bias, opt gelu). A:[T,K] bf16, W:[E,N,K] bf16.
// PIGGY: blockIdx.y >= yTiles are cvt blocks (dedicated-last, best measured).
// SINGLEA && OUTBF: LDS-transpose epilogue (coalesced 16B bf16 stores).
template <int GELU, int OUTBF, int PIGGY, int SINGLEA, int WPE>
__global__ __launch_bounds__(256, WPE) void grouped_gemm(
    const unsigned short* __restrict__ A, const unsigned short* __restrict__ W,
    const float* __restrict__ bias, void* __restrict__ Cv,
    const int4* __restrict__ tbl, const int* __restrict__ ntp,
    const int N, const int K,
    const float* __restrict__ pg_src, unsigned short* __restrict__ pg_dst,
    const long pg_n, const int yTiles) {
  constexpr int BKT = 64;
  if (PIGGY && (int)blockIdx.y >= yTiles) {
    const int p = ((int)blockIdx.y - yTiles) * gridDim.x + blockIdx.x;
    const long PB = (long)(gridDim.y - yTiles) * gridDim.x;
    long i = ((long)p * blockDim.x + threadIdx.x) * 8;
    const long stride = PB * blockDim.x * 8;
    for (; i < pg_n; i += stride) cvt8(pg_src, pg_dst, i);
    return;
  }

  const int mt = blockIdx.y;
  const int bx = blockIdx.x;
  if (mt >= *ntp) return;
  const int4 ti = tbl[mt];
  const int e = ti.x, row0 = ti.y, rows = ti.z;
  const int bcol = bx * BN;

  constexpr int SABUF = SINGLEA ? 1 : 2;
  __shared__ alignas(16) unsigned short raw[(SABUF + 2) * BM * BKT];
  auto sA = [&](int b) { return &raw[b * BM * BKT]; };
  auto sB = [&](int b) { return &raw[(SABUF + b) * BN * BKT]; };

  const int tid = threadIdx.x;
  const int lane = tid & 63;
  const int wave = tid >> 6;
  const int wr = wave >> 1;  // 0..1
  const int wc = wave & 1;   // 0..1
  const int lr = lane & 15;
  const int lhi = lane >> 4; // 0..3

  const unsigned short* __restrict__ Wexp = W + (size_t)e * N * K;

  // ---- staging geometry (dest linear: wave*1024 + lane*16 + i*4096) --------
  constexpr int CH  = BKT / 8;     // 8 chunks of 16B per row
  constexpr int LPM = BKT / 16;    // 4 gload16 per matrix per thread
  constexpr int RPL = 2048 / BKT;  // 32 rows per load-block
  const int srow = wave * 8 + (lane >> 3);
  const int chn = lane & (CH - 1);
  const int cg = chn ^ (srow & (CH - 1));   // inverse swizzle, thread-constant

  const unsigned short* gA[LPM];
  const unsigned short* gB[LPM];
#pragma unroll
  for (int i = 0; i < LPM; ++i) {
    const int rA = srow + i * RPL;
    const int rc = rA < rows ? rA : rows - 1;     // clamp inside segment
    gA[i] = A + (size_t)(row0 + rc) * K + cg * 8;
    gB[i] = Wexp + (size_t)(bcol + srow + i * RPL) * K + cg * 8;
  }

  auto stage = [&](int kt, int bA, int bB) {
    char* da = (char*)sA(bA) + wave * 1024;
    char* db = (char*)sB(bB) + wave * 1024;
#pragma unroll
    for (int i = 0; i < LPM; ++i) {
      gload16(gA[i] + kt * BKT, da + i * 4096);
      gload16(gB[i] + kt * BKT, db + i * 4096);
    }
  };

  // ---- LDS read addressing (swizzled; measured conflict-free at BK=64) -----
  constexpr int KH = BKT / 32;     // 2 k-steps of 32 per tile
  int swo[KH];
#pragma unroll
  for (int kh = 0; kh < KH; ++kh)
    swo[kh] = ((kh * 4 + lhi) ^ (lr & (CH - 1))) * 8;
  const int aRowB = wr * 64 + lr;
  const int bRowB = wc * 64 + lr;

  f32x4 acc[4][4] = {};
  const int nk = K / BKT;

  stage(0, 0, 0);
  __syncthreads();

  int buf = 0;
  if constexpr (SINGLEA) {
    // A single-buffered (L2-hot), B double-buffered (cold stream).
    for (int t = 0; t < nk; ++t) {
      bf16x8 af[4][KH], bfr[4][KH];
#pragma unroll
      for (int m = 0; m < 4; ++m) {
        const unsigned short* rp = &sA(0)[(aRowB + m * 16) * BKT];
#pragma unroll
        for (int kh = 0; kh < KH; ++kh)
          af[m][kh] = *reinterpret_cast<const bf16x8*>(rp + swo[kh]);
      }
#pragma unroll
      for (int n = 0; n < 4; ++n) {
        const unsigned short* rp = &sB(buf)[(bRowB + n * 16) * BKT];
#pragma unroll
        for (int kh = 0; kh < KH; ++kh)
          bfr[n][kh] = *reinterpret_cast<const bf16x8*>(rp + swo[kh]);
      }
      __syncthreads();               // all waves' reads retired -> sA reusable
      if (t + 1 < nk) stage(t + 1, 0, buf ^ 1);
#pragma unroll
      for (int kh = 0; kh < KH; ++kh)
#pragma unroll
        for (int m = 0; m < 4; ++m)
#pragma unroll
          for (int n = 0; n < 4; ++n)
            acc[m][n] = __builtin_amdgcn_mfma_f32_16x16x32_bf16(
                af[m][kh], bfr[n][kh], acc[m][n], 0, 0, 0);
      __syncthreads();               // vmcnt drain: staged tile visible
      buf ^= 1;
    }
  } else {
    // Plain double-buffer (R13-proven for GEMM2).
    for (int t = 0; t < nk; ++t) {
      if (t + 1 < nk) stage(t + 1, buf ^ 1, buf ^ 1);
#pragma unroll
      for (int kh = 0; kh < KH; ++kh) {
        bf16x8 af[4], bfr[4];
#pragma unroll
        for (int m = 0; m < 4; ++m)
          af[m] = *reinterpret_cast<const bf16x8*>(
              &sA(buf)[(aRowB + m * 16) * BKT + swo[kh]]);
#pragma unroll
        for (int n = 0; n < 4; ++n)
          bfr[n] = *reinterpret_cast<const bf16x8*>(
              &sB(buf)[(bRowB + n * 16) * BKT + swo[kh]]);
#pragma unroll
        for (int m = 0; m < 4; ++m)
#pragma unroll
          for (int n = 0; n < 4; ++n)
            acc[m][n] = __builtin_amdgcn_mfma_f32_16x16x32_bf16(
                af[m], bfr[n], acc[m][n], 0, 0, 0);
      }
      __syncthreads();
      buf ^= 1;
    }
  }

  // Epilogue. C/D layout (m89): col = lane&15, row = (lane>>4)*4 + reg.
  const float* __restrict__ be = bias + (size_t)e * N;
  if constexpr (SINGLEA && OUTBF) {
    // LDS-transpose epilogue: gelu+pack to LDS tile, then coalesced 16B out.
    unsigned short* tb = raw;
#pragma unroll
    for (int n = 0; n < 4; ++n) {
      const int col = wc * 64 + n * 16 + lr;         // tile-local 0..127
      const float bv = be[bcol + col];
#pragma unroll
      for (int m = 0; m < 4; ++m) {
#pragma unroll
        for (int j = 0; j < 4; ++j) {
          const int row = wr * 64 + m * 16 + (lhi << 2) + j;
          float v = acc[m][n][j] + bv;
          if (GELU) v = fast_gelu(v);
          tb[row * BN + col] = f2bf(v);
        }
      }
    }
    __syncthreads();
    unsigned short* __restrict__ hout = (unsigned short*)Cv;
#pragma unroll
    for (int i = 0; i < 8; ++i) {
      const int flat = i * 256 + tid;
      const int row = flat >> 4;                     // 16 threads per 256B row
      const int ch = flat & 15;
      if (row < rows)
        *reinterpret_cast<u16x8*>(&hout[(size_t)(row0 + row) * N + bcol + ch * 8]) =
            *reinterpret_cast<const u16x8*>(&tb[row * BN + ch * 8]);
    }
  } else {
    const int colBase = bcol + wc * 64 + lr;
    const int rowBase = wr * 64 + (lhi << 2);
#pragma unroll
    for (int n = 0; n < 4; ++n) {
      const int col = colBase + n * 16;
      const float bv = be[col];
#pragma unroll
      for (int m = 0; m < 4; ++m) {
        const int r0 = rowBase + m * 16;
#pragma unroll
        for (int j = 0; j < 4; ++j) {
          const int rr = r0 + j;
          if (rr < rows) {
            float v = acc[m][n][j] + bv;
            if (GELU) v = fast_gelu(v);
            const size_t idx = (size_t)(row0 + rr) * N + col;
            if (OUTBF) ((unsigned short*)Cv)[idx] = f2bf(v);
            else       ((float*)Cv)[idx] = v;
          }
        }
      }
    }
  }
}

extern "C" void kernel_launch(void* const* d_in, const int* in_sizes, int n_in,
                              void* d_out, int out_size, void* d_ws, size_t ws_size,
                              hipStream_t stream) {
  const float* inp = (const float*)d_in[0];
  const float* w1  = (const float*)d_in[1];
  const float* b1  = (const float*)d_in[2];
  const float* w2  = (const float*)d_in[3];
  const float* b2  = (const float*)d_in[4];
  const int*   cnt = (const int*)d_in[5];

  const int E = in_sizes[5];
  const int H = in_sizes[2] / E;       // b1 is [E,H]
  const int D = in_sizes[4] / E;       // b2 is [E,D]
  const int T = in_sizes[0] / D;       // inp is [T,D]

  char* ws = (char*)d_ws;
  int4* tbl = (int4*)ws;               // <= 72 entries
  int* ntp = (int*)(ws + 2048);
  size_t off = 4096;
  unsigned short* inp_bf = (unsigned short*)(ws + off); off += (size_t)T * D * 2;
  unsigned short* w1_bf  = (unsigned short*)(ws + off); off += (size_t)E * H * D * 2;
  unsigned short* w2_bf  = (unsigned short*)(ws + off); off += (size_t)E * D * H * 2;
  unsigned short* h_bf   = (unsigned short*)(ws + off); off += (size_t)T * H * 2;
  (void)ws_size; (void)n_in; (void)out_size;

  // cvt(inp)+cvt(w1) + tile-table build, one dispatch (GEMM1 deps).
  cvt2_build<<<2048, 256, 0, stream>>>(inp, inp_bf, (long)T * D,
                                       w1, w1_bf, (long)E * H * D,
                                       cnt, E, tbl, ntp);

  const int maxTiles = T / BM + E;
  // GEMM1: BK=64 single-A (48KB -> 3/CU) + piggy cvt(w2) last + LDS epilogue.
  dim3 g1(H / BN, maxTiles + 8);
  grouped_gemm<1, 1, 1, 1, 3><<<g1, 256, 0, stream>>>(
      inp_bf, w1_bf, b1, h_bf, tbl, ntp, H, D,
      w2, w2_bf, (long)E * D * H, maxTiles);
  // GEMM2: BK=64 plain dbuf (R13-proven ~100us).
  dim3 g2(D / BN, maxTiles);
  grouped_gemm<0, 0, 0, 0, 2><<<g2, 256, 0, stream>>>(
      h_bf, w2_bf, b2, d_out, tbl, ntp, D, H,
      nullptr, nullptr, 0, maxTiles);
}